// Round 1
// baseline (348.072 us; speedup 1.0000x reference)
//
#include <hip/hip_runtime.h>

typedef __bf16 bf16;
typedef __attribute__((ext_vector_type(8))) __bf16 bf16x8;
typedef __attribute__((ext_vector_type(4))) float f32x4;

#define AS1 __attribute__((address_space(1)))
#define AS3 __attribute__((address_space(3)))

// Problem constants
#define BB 2
#define SS 2048
#define DD 1024
#define HH 16
#define HD 64
#define BH (BB*HH)

static __device__ __forceinline__ f32x4 mfma16(bf16x8 a, bf16x8 b, f32x4 c) {
  return __builtin_amdgcn_mfma_f32_16x16x32_bf16(a, b, c, 0, 0, 0);
}

// ---------------- fp32 -> bf16 conversion (vectorized) ----------------
__global__ __launch_bounds__(256) void cvt_bf16(const float* __restrict__ src,
                                                bf16* __restrict__ dst, int n8) {
  int i = blockIdx.x * 256 + threadIdx.x;
  if (i >= n8) return;
  const float4* s = (const float4*)src;
  float4 a = s[2 * i], b = s[2 * i + 1];
  bf16x8 o;
  o[0] = (bf16)a.x; o[1] = (bf16)a.y; o[2] = (bf16)a.z; o[3] = (bf16)a.w;
  o[4] = (bf16)b.x; o[5] = (bf16)b.y; o[6] = (bf16)b.z; o[7] = (bf16)b.w;
  ((bf16x8*)dst)[i] = o;
}

// ---------------- core 128x128 bf16 NT GEMM (C = A * B^T), K mult of 32 ----------------
__device__ __forceinline__ void gemm_core(const bf16* __restrict__ A,
                                          const bf16* __restrict__ Bm, int K,
                                          int m0, int n0, int w, int l,
                                          bf16* sA, bf16* sB, f32x4 (&acc)[4][4]) {
  const int l15 = l & 15, lg = l >> 4;
  const int wr = (w >> 1) * 64, wc = (w & 1) * 64;
  for (int kt = 0; kt < K; kt += 32) {
#pragma unroll
    for (int i = 0; i < 2; ++i) {
      int t = i * 256 + w * 64 + l;
      const bf16* ga = A + (size_t)(m0 + (t >> 2)) * K + kt + (t & 3) * 8;
      const bf16* gb = Bm + (size_t)(n0 + (t >> 2)) * K + kt + (t & 3) * 8;
      __builtin_amdgcn_global_load_lds((const AS1 void*)ga,
                                       (AS3 void*)(sA + (i * 256 + w * 64) * 8), 16, 0, 0);
      __builtin_amdgcn_global_load_lds((const AS1 void*)gb,
                                       (AS3 void*)(sB + (i * 256 + w * 64) * 8), 16, 0, 0);
    }
    __syncthreads();
    bf16x8 af[4], bfr[4];
#pragma unroll
    for (int m = 0; m < 4; ++m)
      af[m] = *(const bf16x8*)(sA + (wr + m * 16 + l15) * 32 + lg * 8);
#pragma unroll
    for (int n = 0; n < 4; ++n)
      bfr[n] = *(const bf16x8*)(sB + (wc + n * 16 + l15) * 32 + lg * 8);
#pragma unroll
    for (int m = 0; m < 4; ++m)
#pragma unroll
      for (int n = 0; n < 4; ++n)
        acc[m][n] = mfma16(af[m], bfr[n], acc[m][n]);
    __syncthreads();
  }
}

// ---------------- batched QKV projection: y = x @ W^T + b, heads layout ----------------
// z=0: Q -> Oq [BH][S][64]; z=1: K -> Ok [BH][S][64]; z=2: V -> Ovt [BH][64][S] (transposed)
__global__ __launch_bounds__(256) void proj_gemm(
    const bf16* __restrict__ Xq, const bf16* __restrict__ Xk, const bf16* __restrict__ Xv,
    const bf16* __restrict__ Wq, const bf16* __restrict__ Wk, const bf16* __restrict__ Wv,
    const float* __restrict__ bq, const float* __restrict__ bk, const float* __restrict__ bv,
    bf16* __restrict__ Oq, bf16* __restrict__ Ok, bf16* __restrict__ Ovt) {
  __shared__ __align__(16) bf16 sA[128 * 32];
  __shared__ __align__(16) bf16 sB[128 * 32];
  const int z = blockIdx.z;
  const bf16* A = (z == 0) ? Xq : ((z == 1) ? Xk : Xv);
  const bf16* W = (z == 0) ? Wq : ((z == 1) ? Wk : Wv);
  const float* bias = (z == 0) ? bq : ((z == 1) ? bk : bv);
  const int tid = threadIdx.x, l = tid & 63, w = tid >> 6;
  const int m0 = blockIdx.y * 128, n0 = blockIdx.x * 128;
  f32x4 acc[4][4] = {};
  gemm_core(A, W, DD, m0, n0, w, l, sA, sB, acc);
  const int l15 = l & 15, lg = l >> 4;
  const int wr = (w >> 1) * 64, wc = (w & 1) * 64;
#pragma unroll
  for (int n = 0; n < 4; ++n) {
    int col = n0 + wc + n * 16 + l15;
    float bb = bias[col];
    int h = col >> 6, d = col & 63;
#pragma unroll
    for (int m = 0; m < 4; ++m) {
#pragma unroll
      for (int r = 0; r < 4; ++r) {
        int row = m0 + wr + m * 16 + lg * 4 + r;
        int b = row >> 11, s = row & (SS - 1);
        float vv = acc[m][n][r] + bb;
        if (z != 2)
          ((z == 0) ? Oq : Ok)[(((size_t)(b * HH + h)) * SS + s) * HD + d] = (bf16)vv;
        else
          Ovt[(((size_t)(b * HH + h)) * HD + d) * SS + s] = (bf16)vv;
      }
    }
  }
}

// ---------------- output projection: out = ctx @ Wo^T + bo (fp32 out) ----------------
__global__ __launch_bounds__(256) void out_gemm(const bf16* __restrict__ A,
                                                const bf16* __restrict__ W,
                                                const float* __restrict__ bias,
                                                float* __restrict__ out) {
  __shared__ __align__(16) bf16 sA[128 * 32];
  __shared__ __align__(16) bf16 sB[128 * 32];
  const int tid = threadIdx.x, l = tid & 63, w = tid >> 6;
  const int m0 = blockIdx.y * 128, n0 = blockIdx.x * 128;
  f32x4 acc[4][4] = {};
  gemm_core(A, W, DD, m0, n0, w, l, sA, sB, acc);
  const int l15 = l & 15, lg = l >> 4;
  const int wr = (w >> 1) * 64, wc = (w & 1) * 64;
#pragma unroll
  for (int n = 0; n < 4; ++n) {
    int col = n0 + wc + n * 16 + l15;
    float bb = bias[col];
#pragma unroll
    for (int m = 0; m < 4; ++m)
#pragma unroll
      for (int r = 0; r < 4; ++r) {
        int row = m0 + wr + m * 16 + lg * 4 + r;
        out[(size_t)row * DD + col] = acc[m][n][r] + bb;
      }
  }
}

// ---------------- pass A: per-column (softmax over q) max & sum ----------------
// scores s[q,k] = (Qh[q,:] . Kh[k,:]) / 8 ; valid iff q > k ; stats over valid q.
// Column S-1 has no valid entries -> stays (m=-1e30, Z=0), never consumed in pass B.
__global__ __launch_bounds__(256) void col_stats(const bf16* __restrict__ Qb,
                                                 const bf16* __restrict__ Kb,
                                                 float* __restrict__ colM,
                                                 float* __restrict__ colZ) {
  const int bh = blockIdx.y;
  const int tid = threadIdx.x, l = tid & 63, w = tid >> 6;
  const int l15 = l & 15, lg = l >> 4;
  const int kw = blockIdx.x * 64 + w * 16;  // this wave's 16 columns
  const bf16* Q = Qb + (size_t)bh * SS * HD;
  const bf16* Kh = Kb + (size_t)bh * SS * HD;
  bf16x8 kb0 = *(const bf16x8*)&Kh[(kw + l15) * HD + lg * 8];
  bf16x8 kb1 = *(const bf16x8*)&Kh[(kw + l15) * HD + 32 + lg * 8];
  const int kcol = kw + l15;
  float m_loc = -1e30f, z_loc = 0.f;
  for (int t = (kw + 1) >> 4; t < SS / 16; ++t) {
    int qb = t * 16;
    bf16x8 a0 = *(const bf16x8*)&Q[(qb + l15) * HD + lg * 8];
    bf16x8 a1 = *(const bf16x8*)&Q[(qb + l15) * HD + 32 + lg * 8];
    f32x4 dacc = {};
    dacc = mfma16(a0, kb0, dacc);
    dacc = mfma16(a1, kb1, dacc);
    float mx = m_loc;
    float sv[4];
#pragma unroll
    for (int r = 0; r < 4; ++r) {
      int q = qb + lg * 4 + r;
      float s = dacc[r] * 0.125f;
      sv[r] = (q > kcol) ? s : -2e30f;  // masked sentinel: exp(-2e30 - (-1e30)) == 0
      mx = fmaxf(mx, sv[r]);
    }
    float zs = 0.f;
#pragma unroll
    for (int r = 0; r < 4; ++r) zs += __expf(sv[r] - mx);
    z_loc = z_loc * __expf(m_loc - mx) + zs;
    m_loc = mx;
  }
  // butterfly-merge the 4 lane-groups (each saw a disjoint subset of q rows)
#pragma unroll
  for (int off = 16; off < 64; off <<= 1) {
    float m2 = __shfl_xor(m_loc, off);
    float z2 = __shfl_xor(z_loc, off);
    float mn = fmaxf(m_loc, m2);
    z_loc = z_loc * __expf(m_loc - mn) + z2 * __expf(m2 - mn);
    m_loc = mn;
  }
  if (l < 16) {
    colM[(size_t)bh * SS + kcol] = m_loc;
    colZ[(size_t)bh * SS + kcol] = z_loc;
  }
}

// ---------------- pass B: ctx[q,:] = sum_{k<q} exp(s-m[k])/Z[k] * V[k,:] + V[S-1,:]/S ----
__global__ __launch_bounds__(256) void attn_ctx(const bf16* __restrict__ Qb,
                                                const bf16* __restrict__ Kb,
                                                const bf16* __restrict__ Vt,
                                                const float* __restrict__ colM,
                                                const float* __restrict__ colZ,
                                                bf16* __restrict__ ctx) {
  __shared__ __align__(16) bf16 pl[4][32 * 40];  // per-wave 32x32 P tile, rows padded to 40
  const int bh = blockIdx.y;
  const int tid = threadIdx.x, l = tid & 63, w = tid >> 6;
  const int l15 = l & 15, lg = l >> 4;
  const int qw = blockIdx.x * 128 + w * 32;  // this wave's 32 q rows
  const bf16* Q = Qb + (size_t)bh * SS * HD;
  const bf16* Kh = Kb + (size_t)bh * SS * HD;
  const bf16* V = Vt + (size_t)bh * HD * SS;  // [64][S]
  const float* cM = colM + (size_t)bh * SS;
  const float* cZ = colZ + (size_t)bh * SS;
  bf16* pw = &pl[w][0];

  bf16x8 qa[2][2];
#pragma unroll
  for (int qt = 0; qt < 2; ++qt)
#pragma unroll
    for (int kk = 0; kk < 2; ++kk)
      qa[qt][kk] = *(const bf16x8*)&Q[(qw + qt * 16 + l15) * HD + kk * 32 + lg * 8];

  f32x4 acc[2][4] = {};

  for (int k0 = 0; k0 <= qw; k0 += 32) {
    // scores: 32q x 32k
    f32x4 sacc[2][2] = {};
#pragma unroll
    for (int kt = 0; kt < 2; ++kt) {
      bf16x8 kb0 = *(const bf16x8*)&Kh[(k0 + kt * 16 + l15) * HD + lg * 8];
      bf16x8 kb1 = *(const bf16x8*)&Kh[(k0 + kt * 16 + l15) * HD + 32 + lg * 8];
#pragma unroll
      for (int qt = 0; qt < 2; ++qt) {
        sacc[qt][kt] = mfma16(qa[qt][0], kb0, sacc[qt][kt]);
        sacc[qt][kt] = mfma16(qa[qt][1], kb1, sacc[qt][kt]);
      }
    }
    // p = exp(s - m[k]) / Z[k], masked to k < q; stash to LDS in PV A-fragment layout
#pragma unroll
    for (int kt = 0; kt < 2; ++kt) {
      int kcol = k0 + kt * 16 + l15;
      float mk = cM[kcol];
      float rz = 1.0f / cZ[kcol];
#pragma unroll
      for (int qt = 0; qt < 2; ++qt) {
#pragma unroll
        for (int r = 0; r < 4; ++r) {
          int q = qw + qt * 16 + lg * 4 + r;
          float p = (kcol < q) ? __expf(sacc[qt][kt][r] * 0.125f - mk) * rz : 0.f;
          pw[(qt * 16 + lg * 4 + r) * 40 + kt * 16 + l15] = (bf16)p;
        }
      }
    }
    asm volatile("s_waitcnt lgkmcnt(0)" ::: "memory");
    __builtin_amdgcn_sched_barrier(0);
    // PV: ctx[32q][64d] += P[32q][32k] @ V[32k][64d] (V accessed via pre-transposed Vt)
    bf16x8 pf[2];
#pragma unroll
    for (int qt = 0; qt < 2; ++qt)
      pf[qt] = *(const bf16x8*)&pw[(qt * 16 + l15) * 40 + lg * 8];
#pragma unroll
    for (int dt = 0; dt < 4; ++dt) {
      bf16x8 vf = *(const bf16x8*)&V[(size_t)(dt * 16 + l15) * SS + k0 + lg * 8];
#pragma unroll
      for (int qt = 0; qt < 2; ++qt)
        acc[qt][dt] = mfma16(pf[qt], vf, acc[qt][dt]);
    }
  }

  // fully-masked column S-1 contributes uniform 1/S to every query row
#pragma unroll
  for (int dt = 0; dt < 4; ++dt) {
    float vlast = (float)V[(size_t)(dt * 16 + l15) * SS + (SS - 1)] * (1.0f / (float)SS);
#pragma unroll
    for (int qt = 0; qt < 2; ++qt)
#pragma unroll
      for (int r = 0; r < 4; ++r) acc[qt][dt][r] += vlast;
  }

  // write ctx [B][S][D] bf16 (seq-major for the output GEMM)
  int b = bh >> 4, h = bh & 15;
#pragma unroll
  for (int qt = 0; qt < 2; ++qt)
#pragma unroll
    for (int r = 0; r < 4; ++r) {
      int q = qw + qt * 16 + lg * 4 + r;
#pragma unroll
      for (int dt = 0; dt < 4; ++dt)
        ctx[((size_t)(b * SS + q)) * DD + h * HD + dt * 16 + l15] = (bf16)acc[qt][dt][r];
    }
}

// ---------------- launcher ----------------
extern "C" void kernel_launch(void* const* d_in, const int* in_sizes, int n_in,
                              void* d_out, int out_size, void* d_ws, size_t ws_size,
                              hipStream_t stream) {
  const float* q  = (const float*)d_in[0];
  const float* k  = (const float*)d_in[1];
  const float* v  = (const float*)d_in[2];
  const float* Wq = (const float*)d_in[3];
  const float* bq = (const float*)d_in[4];
  const float* Wk = (const float*)d_in[5];
  const float* bk = (const float*)d_in[6];
  const float* Wv = (const float*)d_in[7];
  const float* bv = (const float*)d_in[8];
  const float* Wo = (const float*)d_in[9];
  const float* bo = (const float*)d_in[10];

  char* ws = (char*)d_ws;
  const size_t SZP = (size_t)4096 * 1024 * 2;  // 8 MiB: bf16 [4096][1024]
  const size_t SZW = (size_t)1024 * 1024 * 2;  // 2 MiB: bf16 [1024][1024]
  bf16* Qb   = (bf16*)(ws + 0 * SZP);          // [BH][S][64]
  bf16* Kb   = (bf16*)(ws + 1 * SZP);          // [BH][S][64]
  bf16* Vt   = (bf16*)(ws + 2 * SZP);          // [BH][64][S]
  bf16* ctxb = (bf16*)(ws + 3 * SZP);          // [B][S][D]
  bf16* qb16 = (bf16*)(ws + 4 * SZP);
  bf16* kb16 = (bf16*)(ws + 5 * SZP);
  bf16* vb16 = (bf16*)(ws + 6 * SZP);
  bf16* Wqb  = (bf16*)(ws + 7 * SZP + 0 * SZW);
  bf16* Wkb  = (bf16*)(ws + 7 * SZP + 1 * SZW);
  bf16* Wvb  = (bf16*)(ws + 7 * SZP + 2 * SZW);
  bf16* Wob  = (bf16*)(ws + 7 * SZP + 3 * SZW);
  float* colM = (float*)(ws + 7 * SZP + 4 * SZW);
  float* colZ = (float*)(ws + 7 * SZP + 4 * SZW + (size_t)BH * SS * 4);

  const int nW8 = (1024 * 1024) / 8, nX8 = (4096 * 1024) / 8;
  cvt_bf16<<<nW8 / 256, 256, 0, stream>>>(Wq, Wqb, nW8);
  cvt_bf16<<<nW8 / 256, 256, 0, stream>>>(Wk, Wkb, nW8);
  cvt_bf16<<<nW8 / 256, 256, 0, stream>>>(Wv, Wvb, nW8);
  cvt_bf16<<<nW8 / 256, 256, 0, stream>>>(Wo, Wob, nW8);
  cvt_bf16<<<nX8 / 256, 256, 0, stream>>>(q, qb16, nX8);
  cvt_bf16<<<nX8 / 256, 256, 0, stream>>>(k, kb16, nX8);
  cvt_bf16<<<nX8 / 256, 256, 0, stream>>>(v, vb16, nX8);

  proj_gemm<<<dim3(1024 / 128, 4096 / 128, 3), 256, 0, stream>>>(
      qb16, kb16, vb16, Wqb, Wkb, Wvb, bq, bk, bv, Qb, Kb, Vt);

  col_stats<<<dim3(SS / 64, BH), 256, 0, stream>>>(Qb, Kb, colM, colZ);
  attn_ctx<<<dim3(SS / 128, BH), 256, 0, stream>>>(Qb, Kb, Vt, colM, colZ, ctxb);

  out_gemm<<<dim3(1024 / 128, 4096 / 128), 256, 0, stream>>>(ctxb, Wob, bo, (float*)d_out);
}

// Round 2
// 217.982 us; speedup vs baseline: 1.5968x; 1.5968x over previous
//
#include <hip/hip_runtime.h>

typedef __bf16 bf16;
typedef __attribute__((ext_vector_type(8))) __bf16 bf16x8;
typedef __attribute__((ext_vector_type(4))) float f32x4;

#define AS1 __attribute__((address_space(1)))
#define AS3 __attribute__((address_space(3)))

// Problem constants
#define BB 2
#define SS 2048
#define DD 1024
#define HH 16
#define HD 64
#define BH (BB*HH)

static __device__ __forceinline__ f32x4 mfma16(bf16x8 a, bf16x8 b, f32x4 c) {
  return __builtin_amdgcn_mfma_f32_16x16x32_bf16(a, b, c, 0, 0, 0);
}

// ---------------- fp32 -> bf16 conversion (vectorized) ----------------
__global__ __launch_bounds__(256) void cvt_bf16(const float* __restrict__ src,
                                                bf16* __restrict__ dst, int n8) {
  int i = blockIdx.x * 256 + threadIdx.x;
  if (i >= n8) return;
  const float4* s = (const float4*)src;
  float4 a = s[2 * i], b = s[2 * i + 1];
  bf16x8 o;
  o[0] = (bf16)a.x; o[1] = (bf16)a.y; o[2] = (bf16)a.z; o[3] = (bf16)a.w;
  o[4] = (bf16)b.x; o[5] = (bf16)b.y; o[6] = (bf16)b.z; o[7] = (bf16)b.w;
  ((bf16x8*)dst)[i] = o;
}

// ---------------- core 128x128 bf16 NT GEMM (C = A * B^T), K mult of 32 ----------------
__device__ __forceinline__ void gemm_core(const bf16* __restrict__ A,
                                          const bf16* __restrict__ Bm, int K,
                                          int m0, int n0, int w, int l,
                                          bf16* sA, bf16* sB, f32x4 (&acc)[4][4]) {
  const int l15 = l & 15, lg = l >> 4;
  const int wr = (w >> 1) * 64, wc = (w & 1) * 64;
  for (int kt = 0; kt < K; kt += 32) {
#pragma unroll
    for (int i = 0; i < 2; ++i) {
      int t = i * 256 + w * 64 + l;
      const bf16* ga = A + (size_t)(m0 + (t >> 2)) * K + kt + (t & 3) * 8;
      const bf16* gb = Bm + (size_t)(n0 + (t >> 2)) * K + kt + (t & 3) * 8;
      __builtin_amdgcn_global_load_lds((const AS1 void*)ga,
                                       (AS3 void*)(sA + (i * 256 + w * 64) * 8), 16, 0, 0);
      __builtin_amdgcn_global_load_lds((const AS1 void*)gb,
                                       (AS3 void*)(sB + (i * 256 + w * 64) * 8), 16, 0, 0);
    }
    __syncthreads();
    bf16x8 af[4], bfr[4];
#pragma unroll
    for (int m = 0; m < 4; ++m)
      af[m] = *(const bf16x8*)(sA + (wr + m * 16 + l15) * 32 + lg * 8);
#pragma unroll
    for (int n = 0; n < 4; ++n)
      bfr[n] = *(const bf16x8*)(sB + (wc + n * 16 + l15) * 32 + lg * 8);
#pragma unroll
    for (int m = 0; m < 4; ++m)
#pragma unroll
      for (int n = 0; n < 4; ++n)
        acc[m][n] = mfma16(af[m], bfr[n], acc[m][n]);
    __syncthreads();
  }
}

// ---------------- batched QKV projection: y = x @ W^T + b, heads layout ----------------
__global__ __launch_bounds__(256) void proj_gemm(
    const bf16* __restrict__ Xq, const bf16* __restrict__ Xk, const bf16* __restrict__ Xv,
    const bf16* __restrict__ Wq, const bf16* __restrict__ Wk, const bf16* __restrict__ Wv,
    const float* __restrict__ bq, const float* __restrict__ bk, const float* __restrict__ bv,
    bf16* __restrict__ Oq, bf16* __restrict__ Ok, bf16* __restrict__ Ovt) {
  __shared__ __align__(16) bf16 sA[128 * 32];
  __shared__ __align__(16) bf16 sB[128 * 32];
  const int z = blockIdx.z;
  const bf16* A = (z == 0) ? Xq : ((z == 1) ? Xk : Xv);
  const bf16* W = (z == 0) ? Wq : ((z == 1) ? Wk : Wv);
  const float* bias = (z == 0) ? bq : ((z == 1) ? bk : bv);
  const int tid = threadIdx.x, l = tid & 63, w = tid >> 6;
  const int m0 = blockIdx.y * 128, n0 = blockIdx.x * 128;
  f32x4 acc[4][4] = {};
  gemm_core(A, W, DD, m0, n0, w, l, sA, sB, acc);
  const int l15 = l & 15, lg = l >> 4;
  const int wr = (w >> 1) * 64, wc = (w & 1) * 64;
#pragma unroll
  for (int n = 0; n < 4; ++n) {
    int col = n0 + wc + n * 16 + l15;
    float bb = bias[col];
    int h = col >> 6, d = col & 63;
#pragma unroll
    for (int m = 0; m < 4; ++m) {
#pragma unroll
      for (int r = 0; r < 4; ++r) {
        int row = m0 + wr + m * 16 + lg * 4 + r;
        int b = row >> 11, s = row & (SS - 1);
        float vv = acc[m][n][r] + bb;
        if (z != 2)
          ((z == 0) ? Oq : Ok)[(((size_t)(b * HH + h)) * SS + s) * HD + d] = (bf16)vv;
        else
          Ovt[(((size_t)(b * HH + h)) * HD + d) * SS + s] = (bf16)vv;
      }
    }
  }
}

// ---------------- output projection: out = ctx @ Wo^T + bo (fp32 out) ----------------
__global__ __launch_bounds__(256) void out_gemm(const bf16* __restrict__ A,
                                                const bf16* __restrict__ W,
                                                const float* __restrict__ bias,
                                                float* __restrict__ out) {
  __shared__ __align__(16) bf16 sA[128 * 32];
  __shared__ __align__(16) bf16 sB[128 * 32];
  const int tid = threadIdx.x, l = tid & 63, w = tid >> 6;
  const int m0 = blockIdx.y * 128, n0 = blockIdx.x * 128;
  f32x4 acc[4][4] = {};
  gemm_core(A, W, DD, m0, n0, w, l, sA, sB, acc);
  const int l15 = l & 15, lg = l >> 4;
  const int wr = (w >> 1) * 64, wc = (w & 1) * 64;
#pragma unroll
  for (int n = 0; n < 4; ++n) {
    int col = n0 + wc + n * 16 + l15;
    float bb = bias[col];
#pragma unroll
    for (int m = 0; m < 4; ++m)
#pragma unroll
      for (int r = 0; r < 4; ++r) {
        int row = m0 + wr + m * 16 + lg * 4 + r;
        out[(size_t)row * DD + col] = acc[m][n][r] + bb;
      }
  }
}

// ---------------- pass A: per-column (softmax over q) max & sum ----------------
// Paired column strips (x, 31-x) -> uniform work per block.
__global__ __launch_bounds__(256) void col_stats(const bf16* __restrict__ Qb,
                                                 const bf16* __restrict__ Kb,
                                                 float* __restrict__ colM,
                                                 float* __restrict__ colZ) {
  const int bh = blockIdx.y;
  const int tid = threadIdx.x, l = tid & 63, w = tid >> 6;
  const int l15 = l & 15, lg = l >> 4;
  const bf16* Q = Qb + (size_t)bh * SS * HD;
  const bf16* Kh = Kb + (size_t)bh * SS * HD;
#pragma unroll
  for (int half = 0; half < 2; ++half) {
    const int strip = half ? (31 - blockIdx.x) : blockIdx.x;
    const int kw = strip * 64 + w * 16;  // this wave's 16 columns
    bf16x8 kb0 = *(const bf16x8*)&Kh[(kw + l15) * HD + lg * 8];
    bf16x8 kb1 = *(const bf16x8*)&Kh[(kw + l15) * HD + 32 + lg * 8];
    const int kcol = kw + l15;
    float m_loc = -1e30f, z_loc = 0.f;
    for (int t = (kw + 1) >> 4; t < SS / 16; ++t) {
      int qb = t * 16;
      bf16x8 a0 = *(const bf16x8*)&Q[(qb + l15) * HD + lg * 8];
      bf16x8 a1 = *(const bf16x8*)&Q[(qb + l15) * HD + 32 + lg * 8];
      f32x4 dacc = {};
      dacc = mfma16(a0, kb0, dacc);
      dacc = mfma16(a1, kb1, dacc);
      float mx = m_loc;
      float sv[4];
#pragma unroll
      for (int r = 0; r < 4; ++r) {
        int q = qb + lg * 4 + r;
        float s = dacc[r] * 0.125f;
        sv[r] = (q > kcol) ? s : -2e30f;  // masked sentinel
        mx = fmaxf(mx, sv[r]);
      }
      float zs = 0.f;
#pragma unroll
      for (int r = 0; r < 4; ++r) zs += __expf(sv[r] - mx);
      z_loc = z_loc * __expf(m_loc - mx) + zs;
      m_loc = mx;
    }
#pragma unroll
    for (int off = 16; off < 64; off <<= 1) {
      float m2 = __shfl_xor(m_loc, off);
      float z2 = __shfl_xor(z_loc, off);
      float mn = fmaxf(m_loc, m2);
      z_loc = z_loc * __expf(m_loc - mn) + z2 * __expf(m2 - mn);
      m_loc = mn;
    }
    if (l < 16) {
      colM[(size_t)bh * SS + kcol] = m_loc;
      colZ[(size_t)bh * SS + kcol] = z_loc;
    }
  }
}

// ---------------- pass B: balanced, k-split across 4 waves ----------------
// Block handles q-tile pair (t, 31-t), 64 rows each -> uniform 66 k-chunks/block.
// Each wave computes the full 64q x 64d partial ctx over a strided k subset;
// partials merged via LDS tree; wave 0 adds V[S-1]/S and writes ctx.
__global__ __launch_bounds__(256) void attn_ctx(const bf16* __restrict__ Qb,
                                                const bf16* __restrict__ Kb,
                                                const bf16* __restrict__ Vt,
                                                const float* __restrict__ colM,
                                                const float* __restrict__ colZ,
                                                bf16* __restrict__ ctx) {
  __shared__ __align__(16) bf16 pl[4][64 * 40];  // per-wave 64x32 P tile, rows padded to 40
  __shared__ __align__(16) float red[64 * 68];   // reduction buffer [d][q], pitch 68
  float* bufA = red;
  float* bufB = (float*)&pl[0][0];               // alias: pl idle during reduction (20480B >= 17408B)
  const int bh = blockIdx.y;
  const int tid = threadIdx.x, l = tid & 63, w = tid >> 6;
  const int l15 = l & 15, lg = l >> 4;
  const bf16* Q = Qb + (size_t)bh * SS * HD;
  const bf16* Kh = Kb + (size_t)bh * SS * HD;
  const bf16* V = Vt + (size_t)bh * HD * SS;  // [64][S]
  const float* cM = colM + (size_t)bh * SS;
  const float* cZ = colZ + (size_t)bh * SS;
  bf16* pw = &pl[w][0];
  const int b = bh >> 4, h = bh & 15;

  for (int half = 0; half < 2; ++half) {
    const int t = half ? (31 - blockIdx.x) : blockIdx.x;
    const int q0 = t * 64;

    bf16x8 qa[4][2];
#pragma unroll
    for (int qt = 0; qt < 4; ++qt)
#pragma unroll
      for (int kk = 0; kk < 2; ++kk)
        qa[qt][kk] = *(const bf16x8*)&Q[(q0 + qt * 16 + l15) * HD + kk * 32 + lg * 8];

    f32x4 acc[4][4] = {};  // [qt][dt]
    const int kend = q0 + 64;
    for (int k0 = w * 32; k0 < kend; k0 += 128) {
      // scores: 64q x 32k
      f32x4 sacc[4][2] = {};
#pragma unroll
      for (int kt = 0; kt < 2; ++kt) {
        bf16x8 kb0 = *(const bf16x8*)&Kh[(k0 + kt * 16 + l15) * HD + lg * 8];
        bf16x8 kb1 = *(const bf16x8*)&Kh[(k0 + kt * 16 + l15) * HD + 32 + lg * 8];
#pragma unroll
        for (int qt = 0; qt < 4; ++qt) {
          sacc[qt][kt] = mfma16(qa[qt][0], kb0, sacc[qt][kt]);
          sacc[qt][kt] = mfma16(qa[qt][1], kb1, sacc[qt][kt]);
        }
      }
      // prefetch V frags (independent of scores)
      bf16x8 vf[4];
#pragma unroll
      for (int dt = 0; dt < 4; ++dt)
        vf[dt] = *(const bf16x8*)&V[(size_t)(dt * 16 + l15) * SS + k0 + lg * 8];
      // p = exp(s - m[k]) / Z[k], masked to k < q; stash in PV A-fragment layout
#pragma unroll
      for (int kt = 0; kt < 2; ++kt) {
        int kcol = k0 + kt * 16 + l15;
        float mk = cM[kcol];
        float rz = 1.0f / cZ[kcol];
#pragma unroll
        for (int qt = 0; qt < 4; ++qt) {
#pragma unroll
          for (int r = 0; r < 4; ++r) {
            int q = q0 + qt * 16 + lg * 4 + r;
            float p = (kcol < q) ? __expf(sacc[qt][kt][r] * 0.125f - mk) * rz : 0.f;
            pw[(qt * 16 + lg * 4 + r) * 40 + kt * 16 + l15] = (bf16)p;
          }
        }
      }
      asm volatile("s_waitcnt lgkmcnt(0)" ::: "memory");
      __builtin_amdgcn_sched_barrier(0);
      bf16x8 pf[4];
#pragma unroll
      for (int qt = 0; qt < 4; ++qt)
        pf[qt] = *(const bf16x8*)&pw[(qt * 16 + l15) * 40 + lg * 8];
#pragma unroll
      for (int dt = 0; dt < 4; ++dt)
#pragma unroll
        for (int qt = 0; qt < 4; ++qt)
          acc[qt][dt] = mfma16(pf[qt], vf[dt], acc[qt][dt]);
    }

    // merge 4 partial accumulators: (1)+(3) -> (0)+(2) -> (0)
    __syncthreads();
    if (w == 1 || w == 3) {
      float* buf = (w == 1) ? bufA : bufB;
#pragma unroll
      for (int qt = 0; qt < 4; ++qt)
#pragma unroll
        for (int dt = 0; dt < 4; ++dt)
          *(f32x4*)&buf[(dt * 16 + l15) * 68 + qt * 16 + lg * 4] = acc[qt][dt];
    }
    __syncthreads();
    if (w == 0 || w == 2) {
      float* buf = (w == 0) ? bufA : bufB;
#pragma unroll
      for (int qt = 0; qt < 4; ++qt)
#pragma unroll
        for (int dt = 0; dt < 4; ++dt)
          acc[qt][dt] += *(const f32x4*)&buf[(dt * 16 + l15) * 68 + qt * 16 + lg * 4];
    }
    __syncthreads();
    if (w == 2) {
#pragma unroll
      for (int qt = 0; qt < 4; ++qt)
#pragma unroll
        for (int dt = 0; dt < 4; ++dt)
          *(f32x4*)&bufA[(dt * 16 + l15) * 68 + qt * 16 + lg * 4] = acc[qt][dt];
    }
    __syncthreads();
    if (w == 0) {
#pragma unroll
      for (int qt = 0; qt < 4; ++qt)
#pragma unroll
        for (int dt = 0; dt < 4; ++dt)
          acc[qt][dt] += *(const f32x4*)&bufA[(dt * 16 + l15) * 68 + qt * 16 + lg * 4];
      // fully-masked column S-1 contributes uniform 1/S to every query row
      float vlast[4];
#pragma unroll
      for (int dt = 0; dt < 4; ++dt)
        vlast[dt] = (float)V[(size_t)(dt * 16 + l15) * SS + (SS - 1)] * (1.0f / (float)SS);
#pragma unroll
      for (int qt = 0; qt < 4; ++qt)
#pragma unroll
        for (int r = 0; r < 4; ++r) {
          int q = q0 + qt * 16 + lg * 4 + r;
#pragma unroll
          for (int dt = 0; dt < 4; ++dt)
            ctx[((size_t)(b * SS + q)) * DD + h * HD + dt * 16 + l15] =
                (bf16)(acc[qt][dt][r] + vlast[dt]);
        }
    }
    __syncthreads();  // protect pl/red before next half reuses them
  }
}

// ---------------- launcher ----------------
extern "C" void kernel_launch(void* const* d_in, const int* in_sizes, int n_in,
                              void* d_out, int out_size, void* d_ws, size_t ws_size,
                              hipStream_t stream) {
  const float* q  = (const float*)d_in[0];
  const float* k  = (const float*)d_in[1];
  const float* v  = (const float*)d_in[2];
  const float* Wq = (const float*)d_in[3];
  const float* bq = (const float*)d_in[4];
  const float* Wk = (const float*)d_in[5];
  const float* bk = (const float*)d_in[6];
  const float* Wv = (const float*)d_in[7];
  const float* bv = (const float*)d_in[8];
  const float* Wo = (const float*)d_in[9];
  const float* bo = (const float*)d_in[10];

  char* ws = (char*)d_ws;
  const size_t SZP = (size_t)4096 * 1024 * 2;  // 8 MiB
  const size_t SZW = (size_t)1024 * 1024 * 2;  // 2 MiB
  bf16* Qb   = (bf16*)(ws + 0 * SZP);          // [BH][S][64]
  bf16* Kb   = (bf16*)(ws + 1 * SZP);          // [BH][S][64]
  bf16* Vt   = (bf16*)(ws + 2 * SZP);          // [BH][64][S]
  bf16* ctxb = (bf16*)(ws + 3 * SZP);          // [B][S][D]
  bf16* qb16 = (bf16*)(ws + 4 * SZP);
  bf16* kb16 = (bf16*)(ws + 5 * SZP);
  bf16* vb16 = (bf16*)(ws + 6 * SZP);
  bf16* Wqb  = (bf16*)(ws + 7 * SZP + 0 * SZW);
  bf16* Wkb  = (bf16*)(ws + 7 * SZP + 1 * SZW);
  bf16* Wvb  = (bf16*)(ws + 7 * SZP + 2 * SZW);
  bf16* Wob  = (bf16*)(ws + 7 * SZP + 3 * SZW);
  float* colM = (float*)(ws + 7 * SZP + 4 * SZW);
  float* colZ = (float*)(ws + 7 * SZP + 4 * SZW + (size_t)BH * SS * 4);

  const int nW8 = (1024 * 1024) / 8, nX8 = (4096 * 1024) / 8;
  cvt_bf16<<<nW8 / 256, 256, 0, stream>>>(Wq, Wqb, nW8);
  cvt_bf16<<<nW8 / 256, 256, 0, stream>>>(Wk, Wkb, nW8);
  cvt_bf16<<<nW8 / 256, 256, 0, stream>>>(Wv, Wvb, nW8);
  cvt_bf16<<<nW8 / 256, 256, 0, stream>>>(Wo, Wob, nW8);
  cvt_bf16<<<nX8 / 256, 256, 0, stream>>>(q, qb16, nX8);
  cvt_bf16<<<nX8 / 256, 256, 0, stream>>>(k, kb16, nX8);
  cvt_bf16<<<nX8 / 256, 256, 0, stream>>>(v, vb16, nX8);

  proj_gemm<<<dim3(1024 / 128, 4096 / 128, 3), 256, 0, stream>>>(
      qb16, kb16, vb16, Wqb, Wkb, Wvb, bq, bk, bv, Qb, Kb, Vt);

  col_stats<<<dim3(16, BH), 256, 0, stream>>>(Qb, Kb, colM, colZ);
  attn_ctx<<<dim3(16, BH), 256, 0, stream>>>(Qb, Kb, Vt, colM, colZ, ctxb);

  out_gemm<<<dim3(1024 / 128, 4096 / 128), 256, 0, stream>>>(ctxb, Wob, bo, (float*)d_out);
}